// Round 1
// baseline (380.666 us; speedup 1.0000x reference)
//
#include <hip/hip_runtime.h>
#include <hip/hip_bf16.h>
#include <math.h>

// ODE Euler solver with teacher forcing — R4: latency/occupancy attack.
// Changes vs R3:
//  * 256-thread blocks (4 waves), pairs-only grouping (NT=4) -> LDS 64 KB
//    -> 2 blocks/CU: two independent barrier domains overlap each other's
//    barrier/waitcnt stalls (was 1 block/CU, 5 global stalls per step).
//  * 4 m-tiles per wave per B-fragment read (was 2) in both GEMMs ->
//    halves the LDS state-read duplication per chain-step.
//  * 4 barriers/step (was 5); mm1(ch1) issued inside mm2(ch0)'s barrier
//    region -> two independent MFMA streams for ILP.

using bf16x8 = __attribute__((ext_vector_type(8))) short;   // 8 bf16
using f32x4  = __attribute__((ext_vector_type(4))) float;   // 4 fp32 acc

constexpr int Bb = 64, Cc = 256, Tt = 64, Vv = 25, Hh = 512;
constexpr int TV = Tt * Vv;              // 1600
constexpr int NT = 4;                    // max 4 n-tiles (2 chains x 32 cols)
constexpr int MAXCH = Bb * (Tt - 1);     // 4032
constexpr int NGRID = 2080;              // >= worst-case group count (2016)

__device__ __forceinline__ short f2bf(float x) {
  union { float f; unsigned u; } v; v.f = x;
  unsigned r = v.u + 0x7FFFu + ((v.u >> 16) & 1u);
  return (short)(r >> 16);
}
__device__ __forceinline__ float fast_tanh(float x) {
  float e = __expf(2.f * x);
  return 1.f - 2.f * __builtin_amdgcn_rcpf(e + 1.f);
}

// ---- fused prepack (blocks 0..1023) + plan (block 1024) ----
// A-frag (16x16x32): lane holds A[m=lane&15][k=(lane>>4)*8+j].
// a1p: A=W1^T (M=H: 32 mt, K=C: 8 kt):  idx ((kt*32+mt)*64+lane)*8+j
// a2p: A=W2^T (M=C: 16 mt, K=H: 16 kt): idx ((kt*16+mt)*64+lane)*8+j
// plan: chains counting-sorted by len desc; hdr = {n1 solos (len>=5), npair}.
__global__ void prep_kernel(const float* __restrict__ W1,
                            const float* __restrict__ W2,
                            const float* __restrict__ tf,
                            short* __restrict__ a1p,
                            short* __restrict__ a2p,
                            int* __restrict__ sorted,
                            int* __restrict__ hdr) {
  if (blockIdx.x < 1024) {
    int idx = blockIdx.x * 256 + threadIdx.x;
    if (idx < 131072) {
      int j = idx & 7, lane = (idx >> 3) & 63, mt = (idx >> 9) & 31, kt = idx >> 14;
      int h = mt * 16 + (lane & 15);
      int c = kt * 32 + (lane >> 4) * 8 + j;
      a1p[idx] = f2bf(W1[c * Hh + h]);
    } else {
      int i2 = idx - 131072;
      int j = i2 & 7, lane = (i2 >> 3) & 63, mt = (i2 >> 9) & 15, kt = i2 >> 13;
      int cm = mt * 16 + (lane & 15);
      int hk = kt * 32 + (lane >> 4) * 8 + j;
      a2p[i2] = f2bf(W2[hk * Cc + cm]);
    }
    return;
  }
  // ---- planning block ----
  __shared__ int cnt[64];
  __shared__ int ofs[64];
  int tid = threadIdx.x;
  if (tid < 64) cnt[tid] = 0;
  for (int i = tid; i < MAXCH; i += 256) sorted[i] = 0;
  __syncthreads();
  if (tid < Bb) {
    int b = tid, prev = 0;
    for (int t = 1; t <= 62; t++)
      if (tf[t * Bb + b] >= 0.5f) { atomicAdd(&cnt[t - prev], 1); prev = t; }
    atomicAdd(&cnt[63 - prev], 1);
  }
  __syncthreads();
  if (tid == 0) {
    int acc = 0;
    for (int l = 63; l >= 1; l--) { ofs[l] = acc; acc += cnt[l]; }
    int n1 = 0;
    for (int l = 5; l <= 63; l++) n1 += cnt[l];
    hdr[0] = n1;                      // solos
    hdr[1] = (acc - n1 + 1) >> 1;     // pairs covering the rest
    hdr[2] = acc;                     // total chains (debug)
    hdr[3] = 0;
  }
  __syncthreads();
  if (tid < Bb) {
    int b = tid, prev = 0;
    for (int t = 1; t <= 62; t++) {
      if (tf[t * Bb + b] >= 0.5f) {
        int len = t - prev;
        int p = atomicAdd(&ofs[len], 1);
        sorted[p] = b | (prev << 6) | (len << 12);
        prev = t;
      }
    }
    int len = 63 - prev;
    int p = atomicAdd(&ofs[len], 1);
    sorted[p] = b | (prev << 6) | (len << 12);
  }
}

// ---- Group kernel: 256 threads (4 waves), gsz in {1,2} ----
// LDS B-frag order: elem(k,n) at ((ktile*NT + nt)*64 + (n&15) + 16*((k&31)>>3))*8 + (k&7)
__global__ __launch_bounds__(256, 2) void group_kernel(
    const float* __restrict__ hsrc, const float* __restrict__ b1,
    const float* __restrict__ b2,   const short* __restrict__ a1p,
    const short* __restrict__ a2p,  const int* __restrict__ sorted,
    const int* __restrict__ hdr,    float* __restrict__ out) {
  __shared__ __align__(16) short zB[8 * NT * 64 * 8];   // 32 KB (K=256)
  __shared__ __align__(16) short uB[8 * NT * 64 * 8];   // 32 KB (K-chunk=256)
  __shared__ int s_meta[2];

  const int n1 = hdr[0], npair = hdr[1];
  const int bi = blockIdx.x;
  int start, gsz;
  if (bi < n1)              { start = bi;                 gsz = 1; }
  else if (bi < n1 + npair) { start = n1 + (bi - n1) * 2; gsz = 2; }
  else return;

  const int tid = threadIdx.x;
  if (tid < 2) s_meta[tid] = (tid < gsz) ? sorted[start + tid] : 0;
  __syncthreads();
  const int maxlen = (s_meta[0] >> 12) & 63;
  const int ntMax  = gsz * 2;

  const int lane = tid & 63;
  const int w    = tid >> 6;           // 0..3
  const int m16  = lane & 15;
  const int quad = lane >> 4;

  int len2[2];
  #pragma unroll
  for (int j = 0; j < 2; j++) len2[j] = (s_meta[j] >> 12) & 63;

  f32x4 acc2[4][NT];                // fp32 master state across steps
  f32x4 acc1[4][NT];                // mm1 transient
  int   obase[4][NT];

  // ---- init: z0 = h[b,:,t0,:]; write zB in B-frag order ----
  #pragma unroll
  for (int i = 0; i < 4; i++) {
    const int cbase = (w * 4 + i) * 16 + quad * 4;    // 0..255, mult of 4
    const int ktz = cbase >> 5;
    const int gq  = (cbase >> 3) & 3;
    const int j0  = cbase & 7;
    #pragma unroll
    for (int nt = 0; nt < NT; nt++) {
      if (nt >= ntMax) break;
      const int j  = nt >> 1;
      const int mj = s_meta[j];
      const int bj = mj & 63, t0 = (mj >> 6) & 63;
      const int v  = (nt & 1) * 16 + m16;
      const bool valid = (len2[j] > 0) && (v < Vv);
      const int hb = ((bj * Cc + cbase) * Tt + t0) * Vv + v;
      f32x4 z;
      #pragma unroll
      for (int r = 0; r < 4; r++) z[r] = valid ? hsrc[hb + r * TV] : 0.f;
      acc2[i][nt] = z;
      obase[i][nt] = hb;
      short4 zh;
      zh.x = f2bf(z[0]); zh.y = f2bf(z[1]); zh.z = f2bf(z[2]); zh.w = f2bf(z[3]);
      *(short4*)&zB[((ktz * NT + nt) * 64 + m16 + 16 * gq) * 8 + j0] = zh;
      if (valid && t0 == 0) {
        #pragma unroll
        for (int r = 0; r < 4; r++) out[hb + r * TV] = z[r];
      }
    }
  }
  __syncthreads();

  // mm1 chunk: acc1 = W1[:,chunk]^T z  (4 mtiles per wave per bz read)
  auto MM1 = [&](int chunk) {
    #pragma unroll
    for (int i = 0; i < 4; i++)
      #pragma unroll
      for (int nt = 0; nt < NT; nt++) acc1[i][nt] = (f32x4){0.f, 0.f, 0.f, 0.f};
    #pragma unroll 2
    for (int kt = 0; kt < 8; kt++) {
      const short* ab = a1p + ((kt * 32 + chunk * 16 + w * 4) * 64 + lane) * 8;
      bf16x8 af[4];
      #pragma unroll
      for (int i = 0; i < 4; i++) af[i] = *(const bf16x8*)(ab + i * 512);
      #pragma unroll
      for (int nt = 0; nt < NT; nt++) {
        if (nt >= ntMax) break;
        bf16x8 bz = *(const bf16x8*)&zB[((kt * NT + nt) * 64 + lane) * 8];
        #pragma unroll
        for (int i = 0; i < 4; i++)
          acc1[i][nt] = __builtin_amdgcn_mfma_f32_16x16x32_bf16(af[i], bz, acc1[i][nt], 0, 0, 0);
      }
    }
  };

  // u epilogue -> uB (B-frag order, chunk-local K)
  auto UEPI = [&](int chunk) {
    #pragma unroll
    for (int i = 0; i < 4; i++) {
      const int hl    = (w * 4 + i) * 16 + quad * 4;   // chunk-local h
      const int hglob = chunk * 256 + hl;
      const int ktl = hl >> 5;
      const int gq  = (hl >> 3) & 3;
      const int j0  = hl & 7;
      const float4 b1v = *(const float4*)(b1 + hglob);
      #pragma unroll
      for (int nt = 0; nt < NT; nt++) {
        if (nt >= ntMax) break;
        short4 up;
        up.x = f2bf(fast_tanh(acc1[i][nt][0] + b1v.x));
        up.y = f2bf(fast_tanh(acc1[i][nt][1] + b1v.y));
        up.z = f2bf(fast_tanh(acc1[i][nt][2] + b1v.z));
        up.w = f2bf(fast_tanh(acc1[i][nt][3] + b1v.w));
        *(short4*)&uB[((ktl * NT + nt) * 64 + m16 + 16 * gq) * 8 + j0] = up;
      }
    }
  };

  // mm2 partial: acc2 += W2[chunk]^T u  (4 mtiles per wave per bu read)
  auto MM2 = [&](int chunk) {
    #pragma unroll 2
    for (int ktl = 0; ktl < 8; ktl++) {
      const short* ab = a2p + (((chunk * 8 + ktl) * 16 + w * 4) * 64 + lane) * 8;
      bf16x8 af[4];
      #pragma unroll
      for (int i = 0; i < 4; i++) af[i] = *(const bf16x8*)(ab + i * 512);
      #pragma unroll
      for (int nt = 0; nt < NT; nt++) {
        if (nt >= ntMax) break;
        bf16x8 bu = *(const bf16x8*)&uB[((ktl * NT + nt) * 64 + lane) * 8];
        #pragma unroll
        for (int i = 0; i < 4; i++)
          acc2[i][nt] = __builtin_amdgcn_mfma_f32_16x16x32_bf16(af[i], bu, acc2[i][nt], 0, 0, 0);
      }
    }
  };

  // ---- step loop: 4 barriers/step ----
  for (int s = 0; s < maxlen; s++) {
    #pragma unroll
    for (int i = 0; i < 4; i++) {
      const int cbase = (w * 4 + i) * 16 + quad * 4;
      const float4 bv = *(const float4*)(b2 + cbase);
      #pragma unroll
      for (int nt = 0; nt < NT; nt++) {
        if (nt >= ntMax) break;
        acc2[i][nt][0] += bv.x; acc2[i][nt][1] += bv.y;
        acc2[i][nt][2] += bv.z; acc2[i][nt][3] += bv.w;
      }
    }
    MM1(0);
    UEPI(0);           // safe: prev step's uB readers done at barrier D
    __syncthreads();   // A: uB(ch0) visible
    MM2(0);
    MM1(1);            // independent of uB -> overlaps mm2(ch0) region
    __syncthreads();   // B: all mm2(ch0) uB reads done
    UEPI(1);
    __syncthreads();   // C: uB(ch1) visible
    MM2(1);
    // ---- z epilogue: refresh zB, store alive cols ----
    #pragma unroll
    for (int i = 0; i < 4; i++) {
      const int cbase = (w * 4 + i) * 16 + quad * 4;
      const int ktz = cbase >> 5;
      const int gq  = (cbase >> 3) & 3;
      const int j0  = cbase & 7;
      #pragma unroll
      for (int nt = 0; nt < NT; nt++) {
        if (nt >= ntMax) break;
        short4 zh;
        zh.x = f2bf(acc2[i][nt][0]); zh.y = f2bf(acc2[i][nt][1]);
        zh.z = f2bf(acc2[i][nt][2]); zh.w = f2bf(acc2[i][nt][3]);
        *(short4*)&zB[((ktz * NT + nt) * 64 + m16 + 16 * gq) * 8 + j0] = zh;
        const int v = (nt & 1) * 16 + m16;
        if (v < Vv && s < len2[nt >> 1]) {
          const int o = obase[i][nt] + (s + 1) * Vv;
          out[o]          = acc2[i][nt][0];
          out[o + TV]     = acc2[i][nt][1];
          out[o + 2 * TV] = acc2[i][nt][2];
          out[o + 3 * TV] = acc2[i][nt][3];
        }
      }
    }
    __syncthreads();   // D: zB ready for next step
  }
}

extern "C" void kernel_launch(void* const* d_in, const int* in_sizes, int n_in,
                              void* d_out, int out_size, void* d_ws, size_t ws_size,
                              hipStream_t stream) {
  const float* h_ptr = (const float*)d_in[0];
  const float* W1    = (const float*)d_in[1];
  const float* b1    = (const float*)d_in[2];
  const float* W2    = (const float*)d_in[3];
  const float* b2    = (const float*)d_in[4];
  const float* tf    = (const float*)d_in[5];
  float* out = (float*)d_out;

  short* a1p  = (short*)d_ws;            // 256 KB
  short* a2p  = a1p + 131072;            // 256 KB
  int* sorted = (int*)(a2p + 131072);    // 16 KB
  int* hdr    = sorted + MAXCH;          // 16 B

  prep_kernel<<<1025, 256, 0, stream>>>(W1, W2, tf, a1p, a2p, sorted, hdr);
  group_kernel<<<NGRID, 256, 0, stream>>>(h_ptr, b1, b2, a1p, a2p, sorted, hdr, out);
}